// Round 8
// baseline (396.424 us; speedup 1.0000x reference)
//
#include <hip/hip_runtime.h>
#include <math.h>

// B=4, S=4096 -> 16384 tokens; H=4096; E=64; TOP_K=2
#define TOKENS 16384
#define HDIM 4096
#define NE 64

#define BMT 32                  // tokens per block
#define BK 32                   // k per tile (one mfma k-step)
#define KSPLIT 2                // K slices across grid
#define KSLICE (HDIM / KSPLIT)  // 2048
#define NT (KSLICE / BK)        // 64 tiles; 4-way wave interleave -> 16/wave
#define WP 40                   // LDS row stride bf16 (80 B -> 2-way banks, free)
#define AREG (BMT * WP)         // elems per (hi or lo) wave region = 1280
#define LPAD 68                 // reduce-tile row stride (floats)

typedef float f32x4 __attribute__((ext_vector_type(4)));
typedef int i32x4 __attribute__((ext_vector_type(4)));
typedef __bf16 bf16x8 __attribute__((ext_vector_type(8)));

// f32 -> (hi, lo) bf16 split of 8 elements (verified rounds 2/3/6).
__device__ __forceinline__ void split8(f32x4 v0, f32x4 v1, i32x4& h, i32x4& l) {
  float x[8];
#pragma unroll
  for (int j = 0; j < 4; ++j) { x[j] = v0[j]; x[4 + j] = v1[j]; }
  union { unsigned short u[8]; i32x4 v; } H, L;
#pragma unroll
  for (int j = 0; j < 8; ++j) {
    __bf16 hb = (__bf16)x[j];
    H.u[j] = __builtin_bit_cast(unsigned short, hb);
    L.u[j] = __builtin_bit_cast(unsigned short, (__bf16)(x[j] - (float)hb));
  }
  h = H.v; l = L.v;
}

__device__ __forceinline__ f32x4 mfma_bf16(i32x4 a, i32x4 b, f32x4 c) {
  return __builtin_amdgcn_mfma_f32_16x16x32_bf16(
      __builtin_bit_cast(bf16x8, a), __builtin_bit_cast(bf16x8, b), c, 0, 0, 0);
}

// Pre-split W (64x4096 f32 -> bf16 hi/lo in workspace). ~2 us once. (verified)
__global__ __launch_bounds__(256) void convert_w(const float* __restrict__ W,
                                                 unsigned short* __restrict__ Wh,
                                                 unsigned short* __restrict__ Wl) {
  const int i = (blockIdx.x * 256 + threadIdx.x) * 8;
  f32x4 v0 = *(const f32x4*)(W + i);
  f32x4 v1 = *(const f32x4*)(W + i + 4);
  i32x4 h, l;
  split8(v0, v1, h, l);
  *(i32x4*)(Wh + i) = h;
  *(i32x4*)(Wl + i) = l;
}

// Barrier-free-K-loop GEMM (round-6 design, resubmitted after infra failure):
//  - W fragments gathered DIRECTLY from L2 (1 MiB resident; 16B/lane gather
//    is only fatal from HBM) -> W out of LDS, DS traffic halved.
//  - A staged via wave-PRIVATE LDS regions, waves own k-interleaved tiles
//    (t == wv mod 4): same-wave ds ops are in-order -> no K-loop barriers,
//    16 waves/CU drift freely and hide HBM latency (round-5 killer).
//  - 2-deep A register prefetch; 4 ds_read_b128 -> 24 MFMA per tile.
__global__ __launch_bounds__(256, 4) void router_gemm(const float* __restrict__ A,
                                                      const unsigned short* __restrict__ Wh,
                                                      const unsigned short* __restrict__ Wl,
                                                      float* __restrict__ P) {
  __shared__ __align__(16) unsigned short smem[4 * 2 * AREG];  // 20.5 KiB

  const int tid = threadIdx.x;
  const int bt = blockIdx.x;   // token tile (32 tokens)
  const int ks = blockIdx.y;   // K slice
  const int lane = tid & 63;
  const int wv = tid >> 6;     // wave = k-interleave index (tiles t==wv mod 4)

  // staging map (per wave): lane -> row = lane>>1, k-half = lane&1 (16 f32)
  const int srow = lane >> 1;
  const int sh = lane & 1;
  const float* Ab = A + (size_t)(bt * BMT + srow) * HDIM + ks * KSLICE + sh * 16;

  unsigned short* AhS = smem + wv * 2 * AREG;  // wave-private hi region
  unsigned short* AlS = AhS + AREG;            // wave-private lo region
  const int soff = srow * WP + sh * 16;

  // fragment map (verified): A-frag lane l -> A[l&15][(l>>4)*8 + j]
  const int l15 = lane & 15;
  const int fko = lane >> 4;
  const unsigned short* Whp = Wh + (size_t)l15 * HDIM + ks * KSLICE + fko * 8;
  const unsigned short* Wlp = Wl + (size_t)l15 * HDIM + ks * KSLICE + fko * 8;

  f32x4 acc[2][4];  // [token-16-tile][expert-16-tile]
#pragma unroll
  for (int m = 0; m < 2; ++m)
#pragma unroll
    for (int e = 0; e < 4; ++e) acc[m][e] = (f32x4){0.f, 0.f, 0.f, 0.f};

  f32x4 rc[4], rn[4];  // 2-deep A prefetch (16 f32 each)

  auto loadA = [&](int s, f32x4* r) {
    const int kc = (wv + 4 * s) * BK;
#pragma unroll
    for (int i = 0; i < 4; ++i) r[i] = *(const f32x4*)(Ab + kc + 4 * i);
  };

  loadA(0, rc);

  for (int s = 0; s < NT / 4; ++s) {
    const int kc = (wv + 4 * s) * BK;

    // stage current A tile into private LDS (2x split8 -> 4 b128 writes)
    i32x4 h0, l0, h1, l1;
    split8(rc[0], rc[1], h0, l0);
    split8(rc[2], rc[3], h1, l1);
    *(i32x4*)&AhS[soff] = h0;
    *(i32x4*)&AhS[soff + 8] = h1;
    *(i32x4*)&AlS[soff] = l0;
    *(i32x4*)&AlS[soff + 8] = l1;

    // prefetch next A tile (HBM latency hides under this tile's work)
    const bool more = (s + 1 < NT / 4);
    if (more) loadA(s + 1, rn);

    // A fragments from private LDS (same-wave ds ordering: no barrier)
    i32x4 fah[2], fal[2];
#pragma unroll
    for (int m = 0; m < 2; ++m) {
      const int off = (m * 16 + l15) * WP + fko * 8;
      fah[m] = *(const i32x4*)&AhS[off];
      fal[m] = *(const i32x4*)&AlS[off];
    }

    // W fragments direct from L2, per expert tile; 3-term split math (verified)
#pragma unroll
    for (int e = 0; e < 4; ++e) {
      i32x4 fwh = *(const i32x4*)(Whp + (size_t)e * 16 * HDIM + kc);
      i32x4 fwl = *(const i32x4*)(Wlp + (size_t)e * 16 * HDIM + kc);
#pragma unroll
      for (int m = 0; m < 2; ++m) {
        acc[m][e] = mfma_bf16(fah[m], fwh, acc[m][e]);
        acc[m][e] = mfma_bf16(fal[m], fwh, acc[m][e]);
        acc[m][e] = mfma_bf16(fah[m], fwl, acc[m][e]);
      }
    }

    if (more) {
#pragma unroll
      for (int i = 0; i < 4; ++i) rc[i] = rn[i];
    }
  }

  // cross-wave reduce: serialized adds into a shared logits tile, then P.
  // C/D layout (verified): col=lane&15, row=(lane>>4)*4+reg.
  __syncthreads();
  float* L = (float*)smem;  // [32][LPAD]
#pragma unroll
  for (int w = 0; w < 4; ++w) {
    if (wv == w) {
#pragma unroll
      for (int m = 0; m < 2; ++m)
#pragma unroll
        for (int e = 0; e < 4; ++e)
#pragma unroll
          for (int r = 0; r < 4; ++r) {
            const int idx = (m * 16 + fko * 4 + r) * LPAD + e * 16 + l15;
            L[idx] = (w == 0) ? acc[m][e][r] : L[idx] + acc[m][e][r];
          }
    }
    __syncthreads();
  }

  // coalesced partial write: P[ks][bt*32 + row][e]
  float* Pb = P + ((size_t)ks * TOKENS + (size_t)bt * BMT) * NE;
  const int rr = tid >> 3;
  const int cc = (tid & 7) * 8;
#pragma unroll
  for (int i = 0; i < 2; ++i) {
    f32x4 v = *(const f32x4*)&L[rr * LPAD + cc + 4 * i];
    *(f32x4*)&Pb[(size_t)rr * NE + cc + 4 * i] = v;
  }
}

// Finalize (round-0/6 verified epilogue, KSPLIT=2): wave = token, lane = expert.
__global__ __launch_bounds__(256) void router_finalize(const float* __restrict__ P,
                                                       float* __restrict__ out) {
  const int lane = threadIdx.x & 63;
  const int wave = threadIdx.x >> 6;
  const int tok = blockIdx.x * 4 + wave;

  float l = 0.f;
#pragma unroll
  for (int s = 0; s < KSPLIT; ++s)
    l += P[((size_t)s * TOKENS + tok) * NE + lane];

  float m = l;
#pragma unroll
  for (int off = 32; off >= 1; off >>= 1) m = fmaxf(m, __shfl_xor(m, off, 64));

  const float e = expf(l - m);
  float sum = e;
#pragma unroll
  for (int off = 32; off >= 1; off >>= 1) sum += __shfl_xor(sum, off, 64);

  const float p = e / sum;
  out[(size_t)tok * NE + lane] = p;

  float m0 = p;
#pragma unroll
  for (int off = 32; off >= 1; off >>= 1) m0 = fmaxf(m0, __shfl_xor(m0, off, 64));
  const unsigned long long b0 = __ballot(p == m0);
  const int i0 = __ffsll(b0) - 1;

  const float pm = (lane == i0) ? -1.f : p;
  float m1 = pm;
#pragma unroll
  for (int off = 32; off >= 1; off >>= 1) m1 = fmaxf(m1, __shfl_xor(m1, off, 64));
  const unsigned long long b1 = __ballot(pm == m1);
  const int i1 = __ffsll(b1) - 1;

  if (lane == 0) {
    float* idxo = out + (size_t)TOKENS * NE + (size_t)tok * 2;
    idxo[0] = (float)i0;
    idxo[1] = (float)i1;
    float* wo = out + (size_t)TOKENS * NE + (size_t)TOKENS * 2 + (size_t)tok * 2;
    const float d = m0 + m1;
    wo[0] = m0 / d;
    wo[1] = m1 / d;
  }
}

extern "C" void kernel_launch(void* const* d_in, const int* in_sizes, int n_in,
                              void* d_out, int out_size, void* d_ws, size_t ws_size,
                              hipStream_t stream) {
  const float* A = (const float*)d_in[0];  // hidden_states [16384, 4096] f32
  const float* W = (const float*)d_in[1];  // gate_weight   [64, 4096] f32
  float* out = (float*)d_out;
  unsigned short* Whi = (unsigned short*)d_ws;          // 512 KiB
  unsigned short* Wlo = Whi + (size_t)NE * HDIM;        // 512 KiB
  float* P = (float*)(Wlo + (size_t)NE * HDIM);         // 8 MiB partials

  convert_w<<<dim3(NE * HDIM / (256 * 8)), 256, 0, stream>>>(W, Whi, Wlo);
  router_gemm<<<dim3(TOKENS / BMT, KSPLIT), 256, 0, stream>>>(A, Whi, Wlo, P);
  router_finalize<<<dim3(TOKENS / 4), 256, 0, stream>>>(P, out);
}